// Round 6
// baseline (493.872 us; speedup 1.0000x reference)
//
#include <hip/hip_runtime.h>
#include <hip/hip_bf16.h>

// ---------------------------------------------------------------------------
// GCN: h1 = relu(gcnconv(x, W1, b1)); h2 = relu(gcnconv(h1, W2, b2));
//      out = h2 @ Wh + bh
// gcnconv(x,W,b)[d] = dinv[d] * ( sum_{e: src->d} hs[src] + hs[d] ) + b
//   where hs = (x@W) * dinv[row],  dinv = rsqrt(indeg + 1)
// CSR built per call (bin-sort for write locality). GEMM: W^T in LDS
// (b128 reads), X via vector float4 broadcast loads, 8 rows/wave.
// ---------------------------------------------------------------------------

#define BIN_B     128
#define BIN_SHIFT 10          // bucket = dst >> 10 (needs N <= 131072)
#define BIN_CHUNK 4096        // edges per k_bin block

__global__ __launch_bounds__(256) void k_zero(int* p, int n) {
  int i = blockIdx.x * blockDim.x + threadIdx.x;
  if (i < n) p[i] = 0;
}

__global__ __launch_bounds__(256) void k_count(const int* __restrict__ dst, int* cnt, int E) {
  int e = blockIdx.x * blockDim.x + threadIdx.x;
  if (e < E) atomicAdd(&cnt[dst[e]], 1);
}

__global__ __launch_bounds__(256) void k_dinv(const int* __restrict__ cnt, float* dinv, int n) {
  int i = blockIdx.x * blockDim.x + threadIdx.x;
  if (i < n) dinv[i] = rsqrtf((float)(cnt[i] + 1));   // +1 self-loop
}

// ---- 3-pass exclusive scan of cnt[n] -> offs[n]
__global__ __launch_bounds__(256) void k_scan1(const int* __restrict__ cnt,
                                               int* offs, int* bsum, int n) {
  __shared__ int sh[256];
  const int t = threadIdx.x;
  const int base = blockIdx.x * 1024 + t * 4;
  int v0 = 0, v1 = 0, v2 = 0, v3 = 0;
  if (base + 0 < n) v0 = cnt[base + 0];
  if (base + 1 < n) v1 = cnt[base + 1];
  if (base + 2 < n) v2 = cnt[base + 2];
  if (base + 3 < n) v3 = cnt[base + 3];
  const int s = v0 + v1 + v2 + v3;
  sh[t] = s;
  __syncthreads();
  for (int d = 1; d < 256; d <<= 1) {
    int x = (t >= d) ? sh[t - d] : 0;
    __syncthreads();
    sh[t] += x;
    __syncthreads();
  }
  int o = sh[t] - s;
  if (t == 255) bsum[blockIdx.x] = sh[255];
  if (base + 0 < n) { offs[base + 0] = o; o += v0; }
  if (base + 1 < n) { offs[base + 1] = o; o += v1; }
  if (base + 2 < n) { offs[base + 2] = o; o += v2; }
  if (base + 3 < n) { offs[base + 3] = o; o += v3; }
}

__global__ __launch_bounds__(256) void k_scan2(int* bsum, int nb) {
  __shared__ int sh[256];
  const int t = threadIdx.x;
  int v = (t < nb) ? bsum[t] : 0;
  sh[t] = v;
  __syncthreads();
  for (int d = 1; d < 256; d <<= 1) {
    int x = (t >= d) ? sh[t - d] : 0;
    __syncthreads();
    sh[t] += x;
    __syncthreads();
  }
  if (t < nb) bsum[t] = sh[t] - v;
}

__global__ __launch_bounds__(256) void k_scan3(int* offs, const int* __restrict__ bsum,
                                               int* cursor, int n) {
  int i = blockIdx.x * blockDim.x + threadIdx.x;
  if (i < n) {
    int o = offs[i] + bsum[i >> 10];
    offs[i] = o;
    cursor[i] = o;
  }
}

// bucket base offsets boff[0..BIN_B] and bin-phase cursors gcur[0..BIN_B)
__global__ __launch_bounds__(256) void k_bases(const int* __restrict__ offs,
                                               int* boff, int* gcur, int n, int E) {
  int t = threadIdx.x;
  if (t <= BIN_B) {
    int v = ((t << BIN_SHIFT) < n) ? offs[t << BIN_SHIFT] : E;
    boff[t] = v;
    if (t < BIN_B) gcur[t] = v;
  }
}

// Phase 1: split edges into BIN_B buckets by dst>>BIN_SHIFT.
__global__ __launch_bounds__(256) void k_bin(
    const int* __restrict__ src, const int* __restrict__ dst,
    int* gcur, int* __restrict__ binned, int E)
{
  __shared__ int  hist[BIN_B];
  __shared__ int  excl[BIN_B];
  __shared__ int  lcur[BIN_B];
  __shared__ int  gbase[BIN_B];
  __shared__ int2 stage[BIN_CHUNK];

  const int t = threadIdx.x;
  const int base = blockIdx.x * BIN_CHUNK;
  const int m = min(BIN_CHUNK, E - base);

  int2 pr[BIN_CHUNK / 256];
  int nmine = 0;
  #pragma unroll
  for (int i = 0; i < BIN_CHUNK / 256; ++i) {
    int idx = t + 256 * i;
    if (idx < m) {
      pr[i].x = src[base + idx];
      pr[i].y = dst[base + idx];
      nmine = i + 1;
    }
  }

  if (t < BIN_B) hist[t] = 0;
  __syncthreads();
  #pragma unroll
  for (int i = 0; i < BIN_CHUNK / 256; ++i)
    if (i < nmine) atomicAdd(&hist[pr[i].y >> BIN_SHIFT], 1);
  __syncthreads();

  const int mycnt = (t < BIN_B) ? hist[t] : 0;
  for (int d = 1; d < BIN_B; d <<= 1) {
    int v = (t < BIN_B && t >= d) ? hist[t - d] : 0;
    __syncthreads();
    if (t < BIN_B) hist[t] += v;
    __syncthreads();
  }
  if (t < BIN_B) {
    int e = hist[t] - mycnt;       // exclusive prefix within block
    excl[t] = e;
    lcur[t] = e;
    gbase[t] = mycnt ? atomicAdd(&gcur[t], mycnt) : 0;
  }
  __syncthreads();

  #pragma unroll
  for (int i = 0; i < BIN_CHUNK / 256; ++i)
    if (i < nmine) {
      int b = pr[i].y >> BIN_SHIFT;
      int p = atomicAdd(&lcur[b], 1);
      stage[p] = pr[i];
    }
  __syncthreads();

  for (int i = t; i < m; i += 256) {
    int2 pp = stage[i];
    int b = pp.y >> BIN_SHIFT;
    binned[gbase[b] + (i - excl[b])] =
        (pp.x << BIN_SHIFT) | (pp.y & ((1 << BIN_SHIFT) - 1));
  }
}

// Phase 2: consume binned edges; bucket b only on blocks with blockIdx%8==b%8
__global__ __launch_bounds__(256) void k_fill2(
    const int* __restrict__ binned, const int* __restrict__ boff,
    int* cursor, int* csr)
{
  const int xcd = blockIdx.x & 7;
  const int tt  = blockIdx.x >> 3;
  const int b   = xcd + 8 * (tt & 15);       // [0, 128)
  const int c   = tt >> 4;                   // chunk 0..7
  const int bstart = boff[b];
  const int bend   = boff[b + 1];
  const int tid_in = c * 256 + threadIdx.x;  // [0, 2048)
  for (int i = bstart + tid_in; i < bend; i += 2048) {
    int v = binned[i];
    int d = (b << BIN_SHIFT) + (v & ((1 << BIN_SHIFT) - 1));
    int s = v >> BIN_SHIFT;
    int slot = atomicAdd(&cursor[d], 1);
    csr[slot] = s;
  }
}

// Fallback single-pass fill
__global__ __launch_bounds__(256) void k_fill(const int* __restrict__ src,
                                              const int* __restrict__ dst,
                                              int* cursor, int* csr, int E) {
  int e = blockIdx.x * blockDim.x + threadIdx.x;
  if (e < E) {
    int p = atomicAdd(&cursor[dst[e]], 1);
    csr[p] = src[e];
  }
}

// Y[row][j] = (sum_k X[row][k] * W[k][j]) [*dinv[row]] [+bias[j]]
// 256 threads = 4 waves; lane = output col j. W^T in LDS [NOUT][K+4]:
// one ds_read_b128 feeds 16 FMAs per row. X via plain vector float4
// (wave-uniform addr -> 1 transaction + L1 broadcast, deep vector-path MLP).
// 8 rows concurrently per wave = 8 independent FMA chains / load streams.
template<int K, int NOUT, bool SCALE, bool BIAS>
__global__ __launch_bounds__(256) void k_gemm(
    const float* __restrict__ X, const float* __restrict__ W,
    const float* __restrict__ dinv, const float* __restrict__ bias,
    float* __restrict__ Y, int nrows)
{
  constexpr int LDW = K + 4;
  __shared__ float WT[NOUT * LDW];
  for (int idx = threadIdx.x; idx < K * NOUT; idx += 256) {
    int k = idx / NOUT, j = idx - k * NOUT;
    WT[j * LDW + k] = W[idx];
  }
  __syncthreads();

  const int wid  = threadIdx.x >> 6;
  const int lane = threadIdx.x & 63;
  const int j    = (NOUT < 64 && lane >= NOUT) ? (NOUT - 1) : lane;
  const float bj = BIAS ? bias[j] : 0.f;
  const float* wrow = &WT[j * LDW];

  const int r0 = (blockIdx.x * 4 + wid) * 8;

  const float* xp0; const float* xp1; const float* xp2; const float* xp3;
  const float* xp4; const float* xp5; const float* xp6; const float* xp7;
  {
    int c;
    c = r0 + 0; if (c >= nrows) c = nrows - 1; xp0 = X + (size_t)c * K;
    c = r0 + 1; if (c >= nrows) c = nrows - 1; xp1 = X + (size_t)c * K;
    c = r0 + 2; if (c >= nrows) c = nrows - 1; xp2 = X + (size_t)c * K;
    c = r0 + 3; if (c >= nrows) c = nrows - 1; xp3 = X + (size_t)c * K;
    c = r0 + 4; if (c >= nrows) c = nrows - 1; xp4 = X + (size_t)c * K;
    c = r0 + 5; if (c >= nrows) c = nrows - 1; xp5 = X + (size_t)c * K;
    c = r0 + 6; if (c >= nrows) c = nrows - 1; xp6 = X + (size_t)c * K;
    c = r0 + 7; if (c >= nrows) c = nrows - 1; xp7 = X + (size_t)c * K;
  }

  float a0 = 0.f, a1 = 0.f, a2 = 0.f, a3 = 0.f;
  float a4 = 0.f, a5 = 0.f, a6 = 0.f, a7 = 0.f;

  #pragma unroll 2
  for (int k = 0; k < K; k += 4) {
    const float4 wv = *(const float4*)(wrow + k);
    const float4 p0 = *(const float4*)(xp0 + k);
    const float4 p1 = *(const float4*)(xp1 + k);
    const float4 p2 = *(const float4*)(xp2 + k);
    const float4 p3 = *(const float4*)(xp3 + k);
    const float4 p4 = *(const float4*)(xp4 + k);
    const float4 p5 = *(const float4*)(xp5 + k);
    const float4 p6 = *(const float4*)(xp6 + k);
    const float4 p7 = *(const float4*)(xp7 + k);
    a0 = fmaf(p0.x, wv.x, a0); a0 = fmaf(p0.y, wv.y, a0);
    a0 = fmaf(p0.z, wv.z, a0); a0 = fmaf(p0.w, wv.w, a0);
    a1 = fmaf(p1.x, wv.x, a1); a1 = fmaf(p1.y, wv.y, a1);
    a1 = fmaf(p1.z, wv.z, a1); a1 = fmaf(p1.w, wv.w, a1);
    a2 = fmaf(p2.x, wv.x, a2); a2 = fmaf(p2.y, wv.y, a2);
    a2 = fmaf(p2.z, wv.z, a2); a2 = fmaf(p2.w, wv.w, a2);
    a3 = fmaf(p3.x, wv.x, a3); a3 = fmaf(p3.y, wv.y, a3);
    a3 = fmaf(p3.z, wv.z, a3); a3 = fmaf(p3.w, wv.w, a3);
    a4 = fmaf(p4.x, wv.x, a4); a4 = fmaf(p4.y, wv.y, a4);
    a4 = fmaf(p4.z, wv.z, a4); a4 = fmaf(p4.w, wv.w, a4);
    a5 = fmaf(p5.x, wv.x, a5); a5 = fmaf(p5.y, wv.y, a5);
    a5 = fmaf(p5.z, wv.z, a5); a5 = fmaf(p5.w, wv.w, a5);
    a6 = fmaf(p6.x, wv.x, a6); a6 = fmaf(p6.y, wv.y, a6);
    a6 = fmaf(p6.z, wv.z, a6); a6 = fmaf(p6.w, wv.w, a6);
    a7 = fmaf(p7.x, wv.x, a7); a7 = fmaf(p7.y, wv.y, a7);
    a7 = fmaf(p7.z, wv.z, a7); a7 = fmaf(p7.w, wv.w, a7);
  }

  float accs[8] = {a0, a1, a2, a3, a4, a5, a6, a7};
  #pragma unroll
  for (int r = 0; r < 8; ++r) {
    const int row = r0 + r;
    if (row < nrows && lane < NOUT) {
      float v = accs[r];
      if constexpr (SCALE) v *= dinv[row];
      if constexpr (BIAS)  v += bj;
      Y[(size_t)row * NOUT + lane] = v;
    }
  }
}

// Pull-aggregate + fused epilogue. One wave per node, lane = feature.
__global__ __launch_bounds__(256) void k_pull(
    const float* __restrict__ hs, const int* __restrict__ csr,
    const int* __restrict__ offs, const int* __restrict__ endo,
    const float* __restrict__ dinv, const float* __restrict__ bias,
    float* __restrict__ out, int n)
{
  const int node = blockIdx.x * 4 + (threadIdx.x >> 6);
  if (node >= n) return;
  const int lane = threadIdx.x & 63;

  const int beg = offs[node];
  const int m   = endo[node] - beg;

  float acc0 = hs[(size_t)node * 64 + lane];   // self term
  float acc1 = 0.f;

  for (int base = 0; base < m; base += 64) {
    const int kk = (m - base < 64) ? (m - base) : 64;
    const int myidx = (base + lane < m) ? csr[beg + base + lane] : 0;
    int i = 0;
    for (; i + 4 <= kk; i += 4) {
      int s0 = __shfl(myidx, i + 0);
      int s1 = __shfl(myidx, i + 1);
      int s2 = __shfl(myidx, i + 2);
      int s3 = __shfl(myidx, i + 3);
      float v0 = hs[(size_t)s0 * 64 + lane];
      float v1 = hs[(size_t)s1 * 64 + lane];
      float v2 = hs[(size_t)s2 * 64 + lane];
      float v3 = hs[(size_t)s3 * 64 + lane];
      acc0 += v0; acc1 += v1; acc0 += v2; acc1 += v3;
    }
    for (; i < kk; ++i) {
      int s = __shfl(myidx, i);
      acc0 += hs[(size_t)s * 64 + lane];
    }
  }
  float v = fmaf(dinv[node], acc0 + acc1, bias[lane]);
  out[(size_t)node * 64 + lane] = fmaxf(v, 0.f);
}

extern "C" void kernel_launch(void* const* d_in, const int* in_sizes, int n_in,
                              void* d_out, int out_size, void* d_ws, size_t ws_size,
                              hipStream_t stream) {
  const float* x  = (const float*)d_in[0];
  const int*   ei = (const int*)d_in[1];
  const float* W1 = (const float*)d_in[2];
  const float* b1 = (const float*)d_in[3];
  const float* W2 = (const float*)d_in[4];
  const float* b2 = (const float*)d_in[5];
  const float* Wh = (const float*)d_in[6];
  const float* bh = (const float*)d_in[7];
  float* out = (float*)d_out;

  const int N = in_sizes[0] / 128;
  const int E = in_sizes[1] / 2;
  const int* src = ei;
  const int* dst = ei + E;

  auto align_up = [](size_t v, size_t a) { return (v + a - 1) & ~(a - 1); };
  char* ws = (char*)d_ws;
  size_t off = 0;
  int*   cnt    = (int*)(ws + off);   off = align_up(off + (size_t)N * 4, 256);
  float* dinv   = (float*)(ws + off); off = align_up(off + (size_t)N * 4, 256);
  int*   offs   = (int*)(ws + off);   off = align_up(off + (size_t)N * 4, 256);
  int*   cursor = (int*)(ws + off);   off = align_up(off + (size_t)N * 4, 256);
  int*   bsum   = (int*)(ws + off);   off = align_up(off + 256 * 4, 256);
  int*   boff   = (int*)(ws + off);   off = align_up(off + (BIN_B + 1) * 4, 256);
  int*   gcur   = (int*)(ws + off);   off = align_up(off + BIN_B * 4, 256);
  int*   csr    = (int*)(ws + off);   off = align_up(off + (size_t)E * 4, 256);
  int*   binned = (int*)(ws + off);   off = align_up(off + (size_t)E * 4, 256);
  float* A      = (float*)(ws + off); off = align_up(off + (size_t)N * 64 * 4, 256);
  float* B      = (float*)(ws + off); off = align_up(off + (size_t)N * 64 * 4, 256);
  (void)ws_size;

  const int TB = 256;
  const int gN = (N + TB - 1) / TB;
  const int gE = (E + TB - 1) / TB;
  const int nb = (N + 1023) / 1024;
  const int gGemm = (N + 31) / 32;              // 8 rows/wave, 4 waves
  const int gPull = (N + 3) / 4;
  const int gBin  = (E + BIN_CHUNK - 1) / BIN_CHUNK;

  // ---- degree + scan ----
  k_zero <<<gN, TB, 0, stream>>>(cnt, N);
  k_count<<<gE, TB, 0, stream>>>(dst, cnt, E);
  k_dinv <<<gN, TB, 0, stream>>>(cnt, dinv, N);
  k_scan1<<<nb, TB, 0, stream>>>(cnt, offs, bsum, N);
  k_scan2<<<1,  TB, 0, stream>>>(bsum, nb);
  k_scan3<<<gN, TB, 0, stream>>>(offs, bsum, cursor, N);

  // ---- CSR fill ----
  if (N <= (1 << (31 - BIN_SHIFT)) && N <= (BIN_B << BIN_SHIFT)) {
    k_bases<<<1, TB, 0, stream>>>(offs, boff, gcur, N, E);
    k_bin  <<<gBin, TB, 0, stream>>>(src, dst, gcur, binned, E);
    k_fill2<<<8 * 16 * 8, TB, 0, stream>>>(binned, boff, cursor, csr);
  } else {
    k_fill <<<gE, TB, 0, stream>>>(src, dst, cursor, csr, E);
  }

  // ---- layer 1 ----  A = hs1 = (x@W1)*dinv ; B = h1
  k_gemm<128, 64, true, false><<<gGemm, TB, 0, stream>>>(x, W1, dinv, nullptr, A, N);
  k_pull<<<gPull, TB, 0, stream>>>(A, csr, offs, cursor, dinv, b1, B, N);

  // ---- layer 2 ----  A = hs2 = (h1@W2)*dinv ; B = h2
  k_gemm<64, 64, true, false><<<gGemm, TB, 0, stream>>>(B, W2, dinv, nullptr, A, N);
  k_pull<<<gPull, TB, 0, stream>>>(A, csr, offs, cursor, dinv, b2, B, N);

  // ---- head ----  out = h2 @ Wh + bh
  k_gemm<64, 40, false, true><<<gGemm, TB, 0, stream>>>(B, Wh, nullptr, bh, out, N);
}

// Round 7
// 347.761 us; speedup vs baseline: 1.4201x; 1.4201x over previous
//
#include <hip/hip_runtime.h>
#include <hip/hip_bf16.h>

// ---------------------------------------------------------------------------
// GCN: h1 = relu(gcnconv(x, W1, b1)); h2 = relu(gcnconv(h1, W2, b2));
//      out = h2 @ Wh + bh
// gcnconv(x,W,b)[d] = dinv[d] * ( sum_{e: src->d} hs[src] + hs[d] ) + b
//   where hs = (x@W) * dinv[row],  dinv = rsqrt(indeg + 1)
// CSR built per call (bin-sort for write locality). GEMM: both operands in
// LDS; 64 rows/block; thread = 4 rows x NC cols (cols tx+16j -> 2-way banks).
// ---------------------------------------------------------------------------

#define BIN_B     128
#define BIN_SHIFT 10          // bucket = dst >> 10 (needs N <= 131072)
#define BIN_CHUNK 4096        // edges per k_bin block

__global__ __launch_bounds__(256) void k_zero(int* p, int n) {
  int i = blockIdx.x * blockDim.x + threadIdx.x;
  if (i < n) p[i] = 0;
}

__global__ __launch_bounds__(256) void k_count(const int* __restrict__ dst, int* cnt, int E) {
  int e = blockIdx.x * blockDim.x + threadIdx.x;
  if (e < E) atomicAdd(&cnt[dst[e]], 1);
}

__global__ __launch_bounds__(256) void k_dinv(const int* __restrict__ cnt, float* dinv, int n) {
  int i = blockIdx.x * blockDim.x + threadIdx.x;
  if (i < n) dinv[i] = rsqrtf((float)(cnt[i] + 1));   // +1 self-loop
}

// ---- 3-pass exclusive scan of cnt[n] -> offs[n]
__global__ __launch_bounds__(256) void k_scan1(const int* __restrict__ cnt,
                                               int* offs, int* bsum, int n) {
  __shared__ int sh[256];
  const int t = threadIdx.x;
  const int base = blockIdx.x * 1024 + t * 4;
  int v0 = 0, v1 = 0, v2 = 0, v3 = 0;
  if (base + 0 < n) v0 = cnt[base + 0];
  if (base + 1 < n) v1 = cnt[base + 1];
  if (base + 2 < n) v2 = cnt[base + 2];
  if (base + 3 < n) v3 = cnt[base + 3];
  const int s = v0 + v1 + v2 + v3;
  sh[t] = s;
  __syncthreads();
  for (int d = 1; d < 256; d <<= 1) {
    int x = (t >= d) ? sh[t - d] : 0;
    __syncthreads();
    sh[t] += x;
    __syncthreads();
  }
  int o = sh[t] - s;
  if (t == 255) bsum[blockIdx.x] = sh[255];
  if (base + 0 < n) { offs[base + 0] = o; o += v0; }
  if (base + 1 < n) { offs[base + 1] = o; o += v1; }
  if (base + 2 < n) { offs[base + 2] = o; o += v2; }
  if (base + 3 < n) { offs[base + 3] = o; o += v3; }
}

__global__ __launch_bounds__(256) void k_scan2(int* bsum, int nb) {
  __shared__ int sh[256];
  const int t = threadIdx.x;
  int v = (t < nb) ? bsum[t] : 0;
  sh[t] = v;
  __syncthreads();
  for (int d = 1; d < 256; d <<= 1) {
    int x = (t >= d) ? sh[t - d] : 0;
    __syncthreads();
    sh[t] += x;
    __syncthreads();
  }
  if (t < nb) bsum[t] = sh[t] - v;
}

__global__ __launch_bounds__(256) void k_scan3(int* offs, const int* __restrict__ bsum,
                                               int* cursor, int n) {
  int i = blockIdx.x * blockDim.x + threadIdx.x;
  if (i < n) {
    int o = offs[i] + bsum[i >> 10];
    offs[i] = o;
    cursor[i] = o;
  }
}

// bucket base offsets boff[0..BIN_B] and bin-phase cursors gcur[0..BIN_B)
__global__ __launch_bounds__(256) void k_bases(const int* __restrict__ offs,
                                               int* boff, int* gcur, int n, int E) {
  int t = threadIdx.x;
  if (t <= BIN_B) {
    int v = ((t << BIN_SHIFT) < n) ? offs[t << BIN_SHIFT] : E;
    boff[t] = v;
    if (t < BIN_B) gcur[t] = v;
  }
}

// Phase 1: split edges into BIN_B buckets by dst>>BIN_SHIFT.
__global__ __launch_bounds__(256) void k_bin(
    const int* __restrict__ src, const int* __restrict__ dst,
    int* gcur, int* __restrict__ binned, int E)
{
  __shared__ int  hist[BIN_B];
  __shared__ int  excl[BIN_B];
  __shared__ int  lcur[BIN_B];
  __shared__ int  gbase[BIN_B];
  __shared__ int2 stage[BIN_CHUNK];

  const int t = threadIdx.x;
  const int base = blockIdx.x * BIN_CHUNK;
  const int m = min(BIN_CHUNK, E - base);

  int2 pr[BIN_CHUNK / 256];
  int nmine = 0;
  #pragma unroll
  for (int i = 0; i < BIN_CHUNK / 256; ++i) {
    int idx = t + 256 * i;
    if (idx < m) {
      pr[i].x = src[base + idx];
      pr[i].y = dst[base + idx];
      nmine = i + 1;
    }
  }

  if (t < BIN_B) hist[t] = 0;
  __syncthreads();
  #pragma unroll
  for (int i = 0; i < BIN_CHUNK / 256; ++i)
    if (i < nmine) atomicAdd(&hist[pr[i].y >> BIN_SHIFT], 1);
  __syncthreads();

  const int mycnt = (t < BIN_B) ? hist[t] : 0;
  for (int d = 1; d < BIN_B; d <<= 1) {
    int v = (t < BIN_B && t >= d) ? hist[t - d] : 0;
    __syncthreads();
    if (t < BIN_B) hist[t] += v;
    __syncthreads();
  }
  if (t < BIN_B) {
    int e = hist[t] - mycnt;       // exclusive prefix within block
    excl[t] = e;
    lcur[t] = e;
    gbase[t] = mycnt ? atomicAdd(&gcur[t], mycnt) : 0;
  }
  __syncthreads();

  #pragma unroll
  for (int i = 0; i < BIN_CHUNK / 256; ++i)
    if (i < nmine) {
      int b = pr[i].y >> BIN_SHIFT;
      int p = atomicAdd(&lcur[b], 1);
      stage[p] = pr[i];
    }
  __syncthreads();

  for (int i = t; i < m; i += 256) {
    int2 pp = stage[i];
    int b = pp.y >> BIN_SHIFT;
    binned[gbase[b] + (i - excl[b])] =
        (pp.x << BIN_SHIFT) | (pp.y & ((1 << BIN_SHIFT) - 1));
  }
}

// Phase 2: consume binned edges; bucket b only on blocks with blockIdx%8==b%8
__global__ __launch_bounds__(256) void k_fill2(
    const int* __restrict__ binned, const int* __restrict__ boff,
    int* cursor, int* csr)
{
  const int xcd = blockIdx.x & 7;
  const int tt  = blockIdx.x >> 3;
  const int b   = xcd + 8 * (tt & 15);       // [0, 128)
  const int c   = tt >> 4;                   // chunk 0..7
  const int bstart = boff[b];
  const int bend   = boff[b + 1];
  const int tid_in = c * 256 + threadIdx.x;  // [0, 2048)
  for (int i = bstart + tid_in; i < bend; i += 2048) {
    int v = binned[i];
    int d = (b << BIN_SHIFT) + (v & ((1 << BIN_SHIFT) - 1));
    int s = v >> BIN_SHIFT;
    int slot = atomicAdd(&cursor[d], 1);
    csr[slot] = s;
  }
}

// Fallback single-pass fill
__global__ __launch_bounds__(256) void k_fill(const int* __restrict__ src,
                                              const int* __restrict__ dst,
                                              int* cursor, int* csr, int E) {
  int e = blockIdx.x * blockDim.x + threadIdx.x;
  if (e < E) {
    int p = atomicAdd(&cursor[dst[e]], 1);
    csr[p] = src[e];
  }
}

// Y[row][j] = (sum_k X[row][k] * W[k][j]) [*dinv[row]] [+bias[j]]
// Block = 64 rows x NOUT cols, 256 threads as (tx = t&15, ty = t>>4).
// Thread: 4 rows (ty*4+i) x NC cols (tx+16*j).  Xs staged in BK=64 slabs,
// coalesced per-lane loads; WT[col][K+4] staged once.  Both LDS read
// patterns are 2-way bank aliased (free): pitch%32==4 -> bank 4*tx / 16*ty.
template<int K, int NOUT, bool SCALE, bool BIAS>
__global__ __launch_bounds__(256) void k_gemm(
    const float* __restrict__ X, const float* __restrict__ W,
    const float* __restrict__ dinv, const float* __restrict__ bias,
    float* __restrict__ Y, int nrows)
{
  constexpr int LDX = 68;                 // 64 + 4
  constexpr int LDW = K + 4;
  constexpr int NC  = (NOUT + 15) / 16;   // cols per thread
  __shared__ float Xs[64 * LDX];
  __shared__ float WT[NC * 16 * LDW];

  const int t  = threadIdx.x;
  const int tx = t & 15;
  const int ty = t >> 4;
  const int r0 = blockIdx.x * 64;

  // stage W^T: W[k][col] -> WT[col][k]
  for (int idx = t; idx < K * NOUT; idx += 256) {
    int k = idx / NOUT, col = idx - k * NOUT;
    WT[col * LDW + k] = W[idx];
  }

  float acc[4][NC];
  #pragma unroll
  for (int i = 0; i < 4; ++i)
    #pragma unroll
    for (int j = 0; j < NC; ++j) acc[i][j] = 0.f;

  for (int kt = 0; kt < K; kt += 64) {
    __syncthreads();                      // WT ready / Xs safe to overwrite
    // stage Xs[64][64] slab, coalesced: 1024 float4 over 256 threads
    #pragma unroll
    for (int it = 0; it < 4; ++it) {
      int f4  = it * 256 + t;
      int row = f4 >> 4;                  // 16 float4 per row
      int kk  = (f4 & 15) * 4;
      int gr  = r0 + row; if (gr >= nrows) gr = nrows - 1;
      *(float4*)&Xs[row * LDX + kk] = *(const float4*)&X[(size_t)gr * K + kt + kk];
    }
    __syncthreads();

    #pragma unroll 4
    for (int k = 0; k < 64; k += 4) {
      float4 xv[4], wv[NC];
      #pragma unroll
      for (int i = 0; i < 4; ++i)
        xv[i] = *(const float4*)&Xs[(ty * 4 + i) * LDX + k];
      #pragma unroll
      for (int j = 0; j < NC; ++j)
        wv[j] = *(const float4*)&WT[(tx + 16 * j) * LDW + kt + k];
      #pragma unroll
      for (int i = 0; i < 4; ++i)
        #pragma unroll
        for (int j = 0; j < NC; ++j) {
          acc[i][j] = fmaf(xv[i].x, wv[j].x, acc[i][j]);
          acc[i][j] = fmaf(xv[i].y, wv[j].y, acc[i][j]);
          acc[i][j] = fmaf(xv[i].z, wv[j].z, acc[i][j]);
          acc[i][j] = fmaf(xv[i].w, wv[j].w, acc[i][j]);
        }
    }
  }

  // epilogue
  #pragma unroll
  for (int i = 0; i < 4; ++i) {
    const int row = r0 + ty * 4 + i;
    if (row >= nrows) continue;
    const float sc = SCALE ? dinv[row] : 1.f;
    #pragma unroll
    for (int j = 0; j < NC; ++j) {
      const int col = tx + 16 * j;
      if (col < NOUT) {
        float v = acc[i][j];
        if constexpr (SCALE) v *= sc;
        if constexpr (BIAS)  v += bias[col];
        Y[(size_t)row * NOUT + col] = v;
      }
    }
  }
}

// Pull-aggregate + fused epilogue. One wave per node, lane = feature.
__global__ __launch_bounds__(256) void k_pull(
    const float* __restrict__ hs, const int* __restrict__ csr,
    const int* __restrict__ offs, const int* __restrict__ endo,
    const float* __restrict__ dinv, const float* __restrict__ bias,
    float* __restrict__ out, int n)
{
  const int node = blockIdx.x * 4 + (threadIdx.x >> 6);
  if (node >= n) return;
  const int lane = threadIdx.x & 63;

  const int beg = offs[node];
  const int m   = endo[node] - beg;

  float acc0 = hs[(size_t)node * 64 + lane];   // self term
  float acc1 = 0.f;

  for (int base = 0; base < m; base += 64) {
    const int kk = (m - base < 64) ? (m - base) : 64;
    const int myidx = (base + lane < m) ? csr[beg + base + lane] : 0;
    int i = 0;
    for (; i + 4 <= kk; i += 4) {
      int s0 = __shfl(myidx, i + 0);
      int s1 = __shfl(myidx, i + 1);
      int s2 = __shfl(myidx, i + 2);
      int s3 = __shfl(myidx, i + 3);
      float v0 = hs[(size_t)s0 * 64 + lane];
      float v1 = hs[(size_t)s1 * 64 + lane];
      float v2 = hs[(size_t)s2 * 64 + lane];
      float v3 = hs[(size_t)s3 * 64 + lane];
      acc0 += v0; acc1 += v1; acc0 += v2; acc1 += v3;
    }
    for (; i < kk; ++i) {
      int s = __shfl(myidx, i);
      acc0 += hs[(size_t)s * 64 + lane];
    }
  }
  float v = fmaf(dinv[node], acc0 + acc1, bias[lane]);
  out[(size_t)node * 64 + lane] = fmaxf(v, 0.f);
}

extern "C" void kernel_launch(void* const* d_in, const int* in_sizes, int n_in,
                              void* d_out, int out_size, void* d_ws, size_t ws_size,
                              hipStream_t stream) {
  const float* x  = (const float*)d_in[0];
  const int*   ei = (const int*)d_in[1];
  const float* W1 = (const float*)d_in[2];
  const float* b1 = (const float*)d_in[3];
  const float* W2 = (const float*)d_in[4];
  const float* b2 = (const float*)d_in[5];
  const float* Wh = (const float*)d_in[6];
  const float* bh = (const float*)d_in[7];
  float* out = (float*)d_out;

  const int N = in_sizes[0] / 128;
  const int E = in_sizes[1] / 2;
  const int* src = ei;
  const int* dst = ei + E;

  auto align_up = [](size_t v, size_t a) { return (v + a - 1) & ~(a - 1); };
  char* ws = (char*)d_ws;
  size_t off = 0;
  int*   cnt    = (int*)(ws + off);   off = align_up(off + (size_t)N * 4, 256);
  float* dinv   = (float*)(ws + off); off = align_up(off + (size_t)N * 4, 256);
  int*   offs   = (int*)(ws + off);   off = align_up(off + (size_t)N * 4, 256);
  int*   cursor = (int*)(ws + off);   off = align_up(off + (size_t)N * 4, 256);
  int*   bsum   = (int*)(ws + off);   off = align_up(off + 256 * 4, 256);
  int*   boff   = (int*)(ws + off);   off = align_up(off + (BIN_B + 1) * 4, 256);
  int*   gcur   = (int*)(ws + off);   off = align_up(off + BIN_B * 4, 256);
  int*   csr    = (int*)(ws + off);   off = align_up(off + (size_t)E * 4, 256);
  int*   binned = (int*)(ws + off);   off = align_up(off + (size_t)E * 4, 256);
  float* A      = (float*)(ws + off); off = align_up(off + (size_t)N * 64 * 4, 256);
  float* B      = (float*)(ws + off); off = align_up(off + (size_t)N * 64 * 4, 256);
  (void)ws_size;

  const int TB = 256;
  const int gN = (N + TB - 1) / TB;
  const int gE = (E + TB - 1) / TB;
  const int nb = (N + 1023) / 1024;
  const int gGemm = (N + 63) / 64;              // 64 rows per block
  const int gPull = (N + 3) / 4;
  const int gBin  = (E + BIN_CHUNK - 1) / BIN_CHUNK;

  // ---- degree + scan ----
  k_zero <<<gN, TB, 0, stream>>>(cnt, N);
  k_count<<<gE, TB, 0, stream>>>(dst, cnt, E);
  k_dinv <<<gN, TB, 0, stream>>>(cnt, dinv, N);
  k_scan1<<<nb, TB, 0, stream>>>(cnt, offs, bsum, N);
  k_scan2<<<1,  TB, 0, stream>>>(bsum, nb);
  k_scan3<<<gN, TB, 0, stream>>>(offs, bsum, cursor, N);

  // ---- CSR fill ----
  if (N <= (1 << (31 - BIN_SHIFT)) && N <= (BIN_B << BIN_SHIFT)) {
    k_bases<<<1, TB, 0, stream>>>(offs, boff, gcur, N, E);
    k_bin  <<<gBin, TB, 0, stream>>>(src, dst, gcur, binned, E);
    k_fill2<<<8 * 16 * 8, TB, 0, stream>>>(binned, boff, cursor, csr);
  } else {
    k_fill <<<gE, TB, 0, stream>>>(src, dst, cursor, csr, E);
  }

  // ---- layer 1 ----  A = hs1 = (x@W1)*dinv ; B = h1
  k_gemm<128, 64, true, false><<<gGemm, TB, 0, stream>>>(x, W1, dinv, nullptr, A, N);
  k_pull<<<gPull, TB, 0, stream>>>(A, csr, offs, cursor, dinv, b1, B, N);

  // ---- layer 2 ----  A = hs2 = (h1@W2)*dinv ; B = h2
  k_gemm<64, 64, true, false><<<gGemm, TB, 0, stream>>>(B, W2, dinv, nullptr, A, N);
  k_pull<<<gPull, TB, 0, stream>>>(A, csr, offs, cursor, dinv, b2, B, N);

  // ---- head ----  out = h2 @ Wh + bh
  k_gemm<64, 40, false, true><<<gGemm, TB, 0, stream>>>(B, Wh, nullptr, bh, out, N);
}

// Round 8
// 264.081 us; speedup vs baseline: 1.8702x; 1.3169x over previous
//
#include <hip/hip_runtime.h>
#include <hip/hip_bf16.h>

// ---------------------------------------------------------------------------
// GCN: h1 = relu(gcnconv(x, W1, b1)); h2 = relu(gcnconv(h1, W2, b2));
//      out = h2 @ Wh + bh
// gcnconv(x,W,b)[d] = dinv[d] * ( sum_{e: src->d} hs[src] + hs[d] ) + b
//   where hs = (x@W) * dinv[row],  dinv = rsqrt(indeg + 1)
// CSR build: bucket-histogram -> bucket-scan -> bin-sort -> per-bucket LDS
// {degree histogram, scan, offs/endo/dinv write, local-cursor scatter}.
// No global scattered atomics anywhere in the build.
// ---------------------------------------------------------------------------

#define BIN_SHIFT 9
#define BN        (1 << BIN_SHIFT)     // 512 nodes per bucket
#define NB_MAX    256
#define BIN_CHUNK 4096                 // edges per k_bin block

__global__ __launch_bounds__(256) void k_zero(int* p, int n) {
  int i = blockIdx.x * blockDim.x + threadIdx.x;
  if (i < n) p[i] = 0;
}

// ---- bucket-level histogram (LDS pre-aggregated)
__global__ __launch_bounds__(256) void k_bhist(const int* __restrict__ dst,
                                               int* bhist, int E, int nb) {
  __shared__ int lh[NB_MAX];
  lh[threadIdx.x] = 0;
  __syncthreads();
  for (int i = blockIdx.x * 256 + threadIdx.x; i < E; i += gridDim.x * 256)
    atomicAdd(&lh[dst[i] >> BIN_SHIFT], 1);
  __syncthreads();
  int v = lh[threadIdx.x];
  if (threadIdx.x < nb && v) atomicAdd(&bhist[threadIdx.x], v);
}

// ---- scan bucket counts -> boff[nb+1], gcur
__global__ __launch_bounds__(256) void k_bscan(const int* __restrict__ bhist,
                                               int* boff, int* gcur, int nb, int E) {
  __shared__ int sh[256];
  const int t = threadIdx.x;
  int v = (t < nb) ? bhist[t] : 0;
  sh[t] = v;
  __syncthreads();
  for (int d = 1; d < 256; d <<= 1) {
    int x = (t >= d) ? sh[t - d] : 0;
    __syncthreads();
    sh[t] += x;
    __syncthreads();
  }
  if (t < nb) { int e = sh[t] - v; boff[t] = e; gcur[t] = e; }
  if (t == 0) boff[nb] = E;
}

// ---- split-sort edges into buckets by dst>>BIN_SHIFT (coalesced drain)
__global__ __launch_bounds__(256) void k_bin(
    const int* __restrict__ src, const int* __restrict__ dst,
    int* gcur, int* __restrict__ binned, int E)
{
  __shared__ int  hist[NB_MAX];
  __shared__ int  excl[NB_MAX];
  __shared__ int  lcur[NB_MAX];
  __shared__ int  gbase[NB_MAX];
  __shared__ int2 stage[BIN_CHUNK];

  const int t = threadIdx.x;
  const int base = blockIdx.x * BIN_CHUNK;
  const int m = min(BIN_CHUNK, E - base);

  int2 pr[BIN_CHUNK / 256];
  int nmine = 0;
  #pragma unroll
  for (int i = 0; i < BIN_CHUNK / 256; ++i) {
    int idx = t + 256 * i;
    if (idx < m) {
      pr[i].x = src[base + idx];
      pr[i].y = dst[base + idx];
      nmine = i + 1;
    }
  }

  hist[t] = 0;
  __syncthreads();
  #pragma unroll
  for (int i = 0; i < BIN_CHUNK / 256; ++i)
    if (i < nmine) atomicAdd(&hist[pr[i].y >> BIN_SHIFT], 1);
  __syncthreads();

  const int mycnt = hist[t];
  for (int d = 1; d < 256; d <<= 1) {
    int v = (t >= d) ? hist[t - d] : 0;
    __syncthreads();
    hist[t] += v;
    __syncthreads();
  }
  {
    int e = hist[t] - mycnt;
    excl[t] = e;
    lcur[t] = e;
    gbase[t] = mycnt ? atomicAdd(&gcur[t], mycnt) : 0;
  }
  __syncthreads();

  #pragma unroll
  for (int i = 0; i < BIN_CHUNK / 256; ++i)
    if (i < nmine) {
      int b = pr[i].y >> BIN_SHIFT;
      int p = atomicAdd(&lcur[b], 1);
      stage[p] = pr[i];
    }
  __syncthreads();

  for (int i = t; i < m; i += 256) {
    int2 pp = stage[i];
    int b = pp.y >> BIN_SHIFT;
    binned[gbase[b] + (i - excl[b])] =
        (pp.x << BIN_SHIFT) | (pp.y & (BN - 1));
  }
}

// ---- per-bucket CSR build: degree hist + scan + offs/endo/dinv + scatter,
// all in LDS. One block per bucket.
__global__ __launch_bounds__(256) void k_csr(
    const int* __restrict__ binned, const int* __restrict__ boff,
    int* __restrict__ offs, int* __restrict__ endo,
    float* __restrict__ dinv, int* __restrict__ csr, int n)
{
  __shared__ int cnt_l[BN];
  __shared__ int tsum[256];
  __shared__ int lcur[BN];
  const int t = threadIdx.x;
  const int b = blockIdx.x;
  const int base = boff[b];
  const int end  = boff[b + 1];
  const int n0 = b << BIN_SHIFT;

  cnt_l[t] = 0; cnt_l[t + 256] = 0;
  __syncthreads();
  for (int i = base + t; i < end; i += 256)
    atomicAdd(&cnt_l[binned[i] & (BN - 1)], 1);
  __syncthreads();

  const int c0 = cnt_l[2 * t];
  const int c1 = cnt_l[2 * t + 1];
  const int s = c0 + c1;
  tsum[t] = s;
  __syncthreads();
  for (int d = 1; d < 256; d <<= 1) {
    int v = (t >= d) ? tsum[t - d] : 0;
    __syncthreads();
    tsum[t] += v;
    __syncthreads();
  }
  const int ex = tsum[t] - s;          // exclusive prefix within bucket
  const int e0 = ex, e1 = ex + c0;
  const int g0 = n0 + 2 * t, g1 = g0 + 1;
  if (g0 < n) {
    offs[g0] = base + e0; endo[g0] = base + e1;
    dinv[g0] = rsqrtf((float)(c0 + 1));
  }
  if (g1 < n) {
    offs[g1] = base + e1; endo[g1] = base + e1 + c1;
    dinv[g1] = rsqrtf((float)(c1 + 1));
  }
  lcur[2 * t] = e0;
  lcur[2 * t + 1] = e1;
  __syncthreads();
  for (int i = base + t; i < end; i += 256) {
    int v = binned[i];
    int p = atomicAdd(&lcur[v & (BN - 1)], 1);
    csr[base + p] = v >> BIN_SHIFT;
  }
}

// ---------------- fallback path (N too big for bucket build) ---------------
__global__ __launch_bounds__(256) void k_count(const int* __restrict__ dst, int* cnt, int E) {
  int e = blockIdx.x * blockDim.x + threadIdx.x;
  if (e < E) atomicAdd(&cnt[dst[e]], 1);
}
__global__ __launch_bounds__(256) void k_dinv(const int* __restrict__ cnt, float* dinv, int n) {
  int i = blockIdx.x * blockDim.x + threadIdx.x;
  if (i < n) dinv[i] = rsqrtf((float)(cnt[i] + 1));
}
__global__ __launch_bounds__(256) void k_scan1(const int* __restrict__ cnt,
                                               int* offs, int* bsum, int n) {
  __shared__ int sh[256];
  const int t = threadIdx.x;
  const int base = blockIdx.x * 1024 + t * 4;
  int v0 = 0, v1 = 0, v2 = 0, v3 = 0;
  if (base + 0 < n) v0 = cnt[base + 0];
  if (base + 1 < n) v1 = cnt[base + 1];
  if (base + 2 < n) v2 = cnt[base + 2];
  if (base + 3 < n) v3 = cnt[base + 3];
  const int s = v0 + v1 + v2 + v3;
  sh[t] = s;
  __syncthreads();
  for (int d = 1; d < 256; d <<= 1) {
    int x = (t >= d) ? sh[t - d] : 0;
    __syncthreads();
    sh[t] += x;
    __syncthreads();
  }
  int o = sh[t] - s;
  if (t == 255) bsum[blockIdx.x] = sh[255];
  if (base + 0 < n) { offs[base + 0] = o; o += v0; }
  if (base + 1 < n) { offs[base + 1] = o; o += v1; }
  if (base + 2 < n) { offs[base + 2] = o; o += v2; }
  if (base + 3 < n) { offs[base + 3] = o; o += v3; }
}
__global__ __launch_bounds__(256) void k_scan2(int* bsum, int nb) {
  __shared__ int sh[256];
  const int t = threadIdx.x;
  int v = (t < nb) ? bsum[t] : 0;
  sh[t] = v;
  __syncthreads();
  for (int d = 1; d < 256; d <<= 1) {
    int x = (t >= d) ? sh[t - d] : 0;
    __syncthreads();
    sh[t] += x;
    __syncthreads();
  }
  if (t < nb) bsum[t] = sh[t] - v;
}
__global__ __launch_bounds__(256) void k_scan3(int* offs, const int* __restrict__ bsum,
                                               int* cursor, int n) {
  int i = blockIdx.x * blockDim.x + threadIdx.x;
  if (i < n) {
    int o = offs[i] + bsum[i >> 10];
    offs[i] = o;
    cursor[i] = o;
  }
}
__global__ __launch_bounds__(256) void k_fill(const int* __restrict__ src,
                                              const int* __restrict__ dst,
                                              int* cursor, int* csr, int E) {
  int e = blockIdx.x * blockDim.x + threadIdx.x;
  if (e < E) {
    int p = atomicAdd(&cursor[dst[e]], 1);
    csr[p] = src[e];
  }
}
// ---------------------------------------------------------------------------

// Y[row][j] = (sum_k X[row][k] * W[k][j]) [*dinv[row]] [+bias[j]]
// Block = 64 rows x NOUT cols, 256 threads as (tx = t&15, ty = t>>4).
// Thread: 4 rows x NC cols (tx+16*j). Xs staged in BK=64 slabs (coalesced),
// WT[col][K+4] staged once. Both LDS reads 2-way bank aliased (free).
template<int K, int NOUT, bool SCALE, bool BIAS>
__global__ __launch_bounds__(256) void k_gemm(
    const float* __restrict__ X, const float* __restrict__ W,
    const float* __restrict__ dinv, const float* __restrict__ bias,
    float* __restrict__ Y, int nrows)
{
  constexpr int LDX = 68;
  constexpr int LDW = K + 4;
  constexpr int NC  = (NOUT + 15) / 16;
  __shared__ float Xs[64 * LDX];
  __shared__ float WT[NC * 16 * LDW];

  const int t  = threadIdx.x;
  const int tx = t & 15;
  const int ty = t >> 4;
  const int r0 = blockIdx.x * 64;

  for (int idx = t; idx < K * NOUT; idx += 256) {
    int k = idx / NOUT, col = idx - k * NOUT;
    WT[col * LDW + k] = W[idx];
  }

  float acc[4][NC];
  #pragma unroll
  for (int i = 0; i < 4; ++i)
    #pragma unroll
    for (int j = 0; j < NC; ++j) acc[i][j] = 0.f;

  for (int kt = 0; kt < K; kt += 64) {
    __syncthreads();
    #pragma unroll
    for (int it = 0; it < 4; ++it) {
      int f4  = it * 256 + t;
      int row = f4 >> 4;
      int kk  = (f4 & 15) * 4;
      int gr  = r0 + row; if (gr >= nrows) gr = nrows - 1;
      *(float4*)&Xs[row * LDX + kk] = *(const float4*)&X[(size_t)gr * K + kt + kk];
    }
    __syncthreads();

    #pragma unroll 4
    for (int k = 0; k < 64; k += 4) {
      float4 xv[4], wv[NC];
      #pragma unroll
      for (int i = 0; i < 4; ++i)
        xv[i] = *(const float4*)&Xs[(ty * 4 + i) * LDX + k];
      #pragma unroll
      for (int j = 0; j < NC; ++j)
        wv[j] = *(const float4*)&WT[(tx + 16 * j) * LDW + kt + k];
      #pragma unroll
      for (int i = 0; i < 4; ++i)
        #pragma unroll
        for (int j = 0; j < NC; ++j) {
          acc[i][j] = fmaf(xv[i].x, wv[j].x, acc[i][j]);
          acc[i][j] = fmaf(xv[i].y, wv[j].y, acc[i][j]);
          acc[i][j] = fmaf(xv[i].z, wv[j].z, acc[i][j]);
          acc[i][j] = fmaf(xv[i].w, wv[j].w, acc[i][j]);
        }
    }
  }

  #pragma unroll
  for (int i = 0; i < 4; ++i) {
    const int row = r0 + ty * 4 + i;
    if (row >= nrows) continue;
    const float sc = SCALE ? dinv[row] : 1.f;
    #pragma unroll
    for (int j = 0; j < NC; ++j) {
      const int col = tx + 16 * j;
      if (col < NOUT) {
        float v = acc[i][j];
        if constexpr (SCALE) v *= sc;
        if constexpr (BIAS)  v += bias[col];
        Y[(size_t)row * NOUT + col] = v;
      }
    }
  }
}

// Pull-aggregate + fused epilogue. One wave per node, lane = feature.
__global__ __launch_bounds__(256) void k_pull(
    const float* __restrict__ hs, const int* __restrict__ csr,
    const int* __restrict__ offs, const int* __restrict__ endo,
    const float* __restrict__ dinv, const float* __restrict__ bias,
    float* __restrict__ out, int n)
{
  const int node = blockIdx.x * 4 + (threadIdx.x >> 6);
  if (node >= n) return;
  const int lane = threadIdx.x & 63;

  const int beg = offs[node];
  const int m   = endo[node] - beg;

  float acc0 = hs[(size_t)node * 64 + lane];   // self term
  float acc1 = 0.f;

  for (int base = 0; base < m; base += 64) {
    const int kk = (m - base < 64) ? (m - base) : 64;
    const int myidx = (base + lane < m) ? csr[beg + base + lane] : 0;
    int i = 0;
    for (; i + 4 <= kk; i += 4) {
      int s0 = __shfl(myidx, i + 0);
      int s1 = __shfl(myidx, i + 1);
      int s2 = __shfl(myidx, i + 2);
      int s3 = __shfl(myidx, i + 3);
      float v0 = hs[(size_t)s0 * 64 + lane];
      float v1 = hs[(size_t)s1 * 64 + lane];
      float v2 = hs[(size_t)s2 * 64 + lane];
      float v3 = hs[(size_t)s3 * 64 + lane];
      acc0 += v0; acc1 += v1; acc0 += v2; acc1 += v3;
    }
    for (; i < kk; ++i) {
      int s = __shfl(myidx, i);
      acc0 += hs[(size_t)s * 64 + lane];
    }
  }
  float v = fmaf(dinv[node], acc0 + acc1, bias[lane]);
  out[(size_t)node * 64 + lane] = fmaxf(v, 0.f);
}

extern "C" void kernel_launch(void* const* d_in, const int* in_sizes, int n_in,
                              void* d_out, int out_size, void* d_ws, size_t ws_size,
                              hipStream_t stream) {
  const float* x  = (const float*)d_in[0];
  const int*   ei = (const int*)d_in[1];
  const float* W1 = (const float*)d_in[2];
  const float* b1 = (const float*)d_in[3];
  const float* W2 = (const float*)d_in[4];
  const float* b2 = (const float*)d_in[5];
  const float* Wh = (const float*)d_in[6];
  const float* bh = (const float*)d_in[7];
  float* out = (float*)d_out;

  const int N = in_sizes[0] / 128;
  const int E = in_sizes[1] / 2;
  const int* src = ei;
  const int* dst = ei + E;

  auto align_up = [](size_t v, size_t a) { return (v + a - 1) & ~(a - 1); };
  char* ws = (char*)d_ws;
  size_t off = 0;
  int*   cnt    = (int*)(ws + off);   off = align_up(off + (size_t)N * 4, 256);
  float* dinv   = (float*)(ws + off); off = align_up(off + (size_t)N * 4, 256);
  int*   offs   = (int*)(ws + off);   off = align_up(off + (size_t)N * 4, 256);
  int*   endo   = (int*)(ws + off);   off = align_up(off + (size_t)N * 4, 256);
  int*   bsum   = (int*)(ws + off);   off = align_up(off + 256 * 4, 256);
  int*   bhist  = (int*)(ws + off);   off = align_up(off + NB_MAX * 4, 256);
  int*   boff   = (int*)(ws + off);   off = align_up(off + (NB_MAX + 1) * 4, 256);
  int*   gcur   = (int*)(ws + off);   off = align_up(off + NB_MAX * 4, 256);
  int*   csr    = (int*)(ws + off);   off = align_up(off + (size_t)E * 4, 256);
  int*   binned = (int*)(ws + off);   off = align_up(off + (size_t)E * 4, 256);
  float* A      = (float*)(ws + off); off = align_up(off + (size_t)N * 64 * 4, 256);
  float* B      = (float*)(ws + off); off = align_up(off + (size_t)N * 64 * 4, 256);
  (void)ws_size;

  const int TB = 256;
  const int gN = (N + TB - 1) / TB;
  const int gE = (E + TB - 1) / TB;
  const int NBk = (N + BN - 1) >> BIN_SHIFT;      // buckets
  const int gGemm = (N + 63) / 64;
  const int gPull = (N + 3) / 4;
  const int gBin  = (E + BIN_CHUNK - 1) / BIN_CHUNK;

  if (NBk <= NB_MAX) {
    // ---- local CSR build (no scattered global atomics) ----
    k_zero <<<1, TB, 0, stream>>>(bhist, NBk);
    k_bhist<<<512, TB, 0, stream>>>(dst, bhist, E, NBk);
    k_bscan<<<1, TB, 0, stream>>>(bhist, boff, gcur, NBk, E);
    k_bin  <<<gBin, TB, 0, stream>>>(src, dst, gcur, binned, E);
    k_csr  <<<NBk, TB, 0, stream>>>(binned, boff, offs, endo, dinv, csr, N);
  } else {
    // ---- fallback: global count/scan/fill ----
    k_zero <<<gN, TB, 0, stream>>>(cnt, N);
    k_count<<<gE, TB, 0, stream>>>(dst, cnt, E);
    k_dinv <<<gN, TB, 0, stream>>>(cnt, dinv, N);
    const int nb1 = (N + 1023) / 1024;
    k_scan1<<<nb1, TB, 0, stream>>>(cnt, offs, bsum, N);
    k_scan2<<<1,  TB, 0, stream>>>(bsum, nb1);
    k_scan3<<<gN, TB, 0, stream>>>(offs, bsum, endo, N);
    k_fill <<<gE, TB, 0, stream>>>(src, dst, endo, csr, E);
  }

  // ---- layer 1 ----  A = hs1 = (x@W1)*dinv ; B = h1
  k_gemm<128, 64, true, false><<<gGemm, TB, 0, stream>>>(x, W1, dinv, nullptr, A, N);
  k_pull<<<gPull, TB, 0, stream>>>(A, csr, offs, endo, dinv, b1, B, N);

  // ---- layer 2 ----  A = hs2 = (h1@W2)*dinv ; B = h2
  k_gemm<64, 64, true, false><<<gGemm, TB, 0, stream>>>(B, W2, dinv, nullptr, A, N);
  k_pull<<<gPull, TB, 0, stream>>>(A, csr, offs, endo, dinv, b2, B, N);

  // ---- head ----  out = h2 @ Wh + bh
  k_gemm<64, 40, false, true><<<gGemm, TB, 0, stream>>>(B, Wh, nullptr, bh, out, N);
}

// Round 9
// 241.141 us; speedup vs baseline: 2.0481x; 1.0951x over previous
//
#include <hip/hip_runtime.h>
#include <hip/hip_bf16.h>

// ---------------------------------------------------------------------------
// GCN: h1 = relu(gcnconv(x, W1, b1)); h2 = relu(gcnconv(h1, W2, b2));
//      out = h2 @ Wh + bh
// gcnconv(x,W,b)[d] = dinv[d] * ( sum_{e: src->d} hs[src] + hs[d] ) + b
//   where hs = (x@W) * dinv[row],  dinv = rsqrt(indeg + 1)
// CSR build: bucket hist -> bucket scan -> bin-sort -> per-bucket LDS CSR.
// hs stored bf16 (RNE) to halve the random-gather bytes in k_pull;
// all accumulation and h1/h2/out remain fp32.
// ---------------------------------------------------------------------------

#define BIN_SHIFT 9
#define BN        (1 << BIN_SHIFT)     // 512 nodes per bucket
#define NB_MAX    256
#define BIN_CHUNK 4096                 // edges per k_bin block

__device__ __forceinline__ float bf2f(unsigned short u) {
  union { unsigned i; float f; } c; c.i = ((unsigned)u) << 16; return c.f;
}
__device__ __forceinline__ unsigned short f2bf(float f) {
  union { float f; unsigned i; } c; c.f = f;
  unsigned r = c.i + 0x7FFFu + ((c.i >> 16) & 1u);   // RNE
  return (unsigned short)(r >> 16);
}

__global__ __launch_bounds__(256) void k_zero(int* p, int n) {
  int i = blockIdx.x * blockDim.x + threadIdx.x;
  if (i < n) p[i] = 0;
}

// ---- bucket-level histogram (LDS pre-aggregated)
__global__ __launch_bounds__(256) void k_bhist(const int* __restrict__ dst,
                                               int* bhist, int E, int nb) {
  __shared__ int lh[NB_MAX];
  lh[threadIdx.x] = 0;
  __syncthreads();
  for (int i = blockIdx.x * 256 + threadIdx.x; i < E; i += gridDim.x * 256)
    atomicAdd(&lh[dst[i] >> BIN_SHIFT], 1);
  __syncthreads();
  int v = lh[threadIdx.x];
  if (threadIdx.x < nb && v) atomicAdd(&bhist[threadIdx.x], v);
}

// ---- scan bucket counts -> boff[nb+1], gcur
__global__ __launch_bounds__(256) void k_bscan(const int* __restrict__ bhist,
                                               int* boff, int* gcur, int nb, int E) {
  __shared__ int sh[256];
  const int t = threadIdx.x;
  int v = (t < nb) ? bhist[t] : 0;
  sh[t] = v;
  __syncthreads();
  for (int d = 1; d < 256; d <<= 1) {
    int x = (t >= d) ? sh[t - d] : 0;
    __syncthreads();
    sh[t] += x;
    __syncthreads();
  }
  if (t < nb) { int e = sh[t] - v; boff[t] = e; gcur[t] = e; }
  if (t == 0) boff[nb] = E;
}

// ---- split-sort edges into buckets by dst>>BIN_SHIFT (coalesced drain)
__global__ __launch_bounds__(256) void k_bin(
    const int* __restrict__ src, const int* __restrict__ dst,
    int* gcur, int* __restrict__ binned, int E)
{
  __shared__ int  hist[NB_MAX];
  __shared__ int  excl[NB_MAX];
  __shared__ int  lcur[NB_MAX];
  __shared__ int  gbase[NB_MAX];
  __shared__ int2 stage[BIN_CHUNK];

  const int t = threadIdx.x;
  const int base = blockIdx.x * BIN_CHUNK;
  const int m = min(BIN_CHUNK, E - base);

  int2 pr[BIN_CHUNK / 256];
  int nmine = 0;
  #pragma unroll
  for (int i = 0; i < BIN_CHUNK / 256; ++i) {
    int idx = t + 256 * i;
    if (idx < m) {
      pr[i].x = src[base + idx];
      pr[i].y = dst[base + idx];
      nmine = i + 1;
    }
  }

  hist[t] = 0;
  __syncthreads();
  #pragma unroll
  for (int i = 0; i < BIN_CHUNK / 256; ++i)
    if (i < nmine) atomicAdd(&hist[pr[i].y >> BIN_SHIFT], 1);
  __syncthreads();

  const int mycnt = hist[t];
  for (int d = 1; d < 256; d <<= 1) {
    int v = (t >= d) ? hist[t - d] : 0;
    __syncthreads();
    hist[t] += v;
    __syncthreads();
  }
  {
    int e = hist[t] - mycnt;
    excl[t] = e;
    lcur[t] = e;
    gbase[t] = mycnt ? atomicAdd(&gcur[t], mycnt) : 0;
  }
  __syncthreads();

  #pragma unroll
  for (int i = 0; i < BIN_CHUNK / 256; ++i)
    if (i < nmine) {
      int b = pr[i].y >> BIN_SHIFT;
      int p = atomicAdd(&lcur[b], 1);
      stage[p] = pr[i];
    }
  __syncthreads();

  for (int i = t; i < m; i += 256) {
    int2 pp = stage[i];
    int b = pp.y >> BIN_SHIFT;
    binned[gbase[b] + (i - excl[b])] =
        (pp.x << BIN_SHIFT) | (pp.y & (BN - 1));
  }
}

// ---- per-bucket CSR build: degree hist + scan + offs/endo/dinv + scatter
__global__ __launch_bounds__(256) void k_csr(
    const int* __restrict__ binned, const int* __restrict__ boff,
    int* __restrict__ offs, int* __restrict__ endo,
    float* __restrict__ dinv, int* __restrict__ csr, int n)
{
  __shared__ int cnt_l[BN];
  __shared__ int tsum[256];
  __shared__ int lcur[BN];
  const int t = threadIdx.x;
  const int b = blockIdx.x;
  const int base = boff[b];
  const int end  = boff[b + 1];
  const int n0 = b << BIN_SHIFT;

  cnt_l[t] = 0; cnt_l[t + 256] = 0;
  __syncthreads();
  for (int i = base + t; i < end; i += 256)
    atomicAdd(&cnt_l[binned[i] & (BN - 1)], 1);
  __syncthreads();

  const int c0 = cnt_l[2 * t];
  const int c1 = cnt_l[2 * t + 1];
  const int s = c0 + c1;
  tsum[t] = s;
  __syncthreads();
  for (int d = 1; d < 256; d <<= 1) {
    int v = (t >= d) ? tsum[t - d] : 0;
    __syncthreads();
    tsum[t] += v;
    __syncthreads();
  }
  const int ex = tsum[t] - s;
  const int e0 = ex, e1 = ex + c0;
  const int g0 = n0 + 2 * t, g1 = g0 + 1;
  if (g0 < n) {
    offs[g0] = base + e0; endo[g0] = base + e1;
    dinv[g0] = rsqrtf((float)(c0 + 1));
  }
  if (g1 < n) {
    offs[g1] = base + e1; endo[g1] = base + e1 + c1;
    dinv[g1] = rsqrtf((float)(c1 + 1));
  }
  lcur[2 * t] = e0;
  lcur[2 * t + 1] = e1;
  __syncthreads();
  for (int i = base + t; i < end; i += 256) {
    int v = binned[i];
    int p = atomicAdd(&lcur[v & (BN - 1)], 1);
    csr[base + p] = v >> BIN_SHIFT;
  }
}

// ---------------- fallback path (N too big for bucket build) ---------------
__global__ __launch_bounds__(256) void k_count(const int* __restrict__ dst, int* cnt, int E) {
  int e = blockIdx.x * blockDim.x + threadIdx.x;
  if (e < E) atomicAdd(&cnt[dst[e]], 1);
}
__global__ __launch_bounds__(256) void k_dinv(const int* __restrict__ cnt, float* dinv, int n) {
  int i = blockIdx.x * blockDim.x + threadIdx.x;
  if (i < n) dinv[i] = rsqrtf((float)(cnt[i] + 1));
}
__global__ __launch_bounds__(256) void k_scan1(const int* __restrict__ cnt,
                                               int* offs, int* bsum, int n) {
  __shared__ int sh[256];
  const int t = threadIdx.x;
  const int base = blockIdx.x * 1024 + t * 4;
  int v0 = 0, v1 = 0, v2 = 0, v3 = 0;
  if (base + 0 < n) v0 = cnt[base + 0];
  if (base + 1 < n) v1 = cnt[base + 1];
  if (base + 2 < n) v2 = cnt[base + 2];
  if (base + 3 < n) v3 = cnt[base + 3];
  const int s = v0 + v1 + v2 + v3;
  sh[t] = s;
  __syncthreads();
  for (int d = 1; d < 256; d <<= 1) {
    int x = (t >= d) ? sh[t - d] : 0;
    __syncthreads();
    sh[t] += x;
    __syncthreads();
  }
  int o = sh[t] - s;
  if (t == 255) bsum[blockIdx.x] = sh[255];
  if (base + 0 < n) { offs[base + 0] = o; o += v0; }
  if (base + 1 < n) { offs[base + 1] = o; o += v1; }
  if (base + 2 < n) { offs[base + 2] = o; o += v2; }
  if (base + 3 < n) { offs[base + 3] = o; o += v3; }
}
__global__ __launch_bounds__(256) void k_scan2(int* bsum, int nb) {
  __shared__ int sh[256];
  const int t = threadIdx.x;
  int v = (t < nb) ? bsum[t] : 0;
  sh[t] = v;
  __syncthreads();
  for (int d = 1; d < 256; d <<= 1) {
    int x = (t >= d) ? sh[t - d] : 0;
    __syncthreads();
    sh[t] += x;
    __syncthreads();
  }
  if (t < nb) bsum[t] = sh[t] - v;
}
__global__ __launch_bounds__(256) void k_scan3(int* offs, const int* __restrict__ bsum,
                                               int* cursor, int n) {
  int i = blockIdx.x * blockDim.x + threadIdx.x;
  if (i < n) {
    int o = offs[i] + bsum[i >> 10];
    offs[i] = o;
    cursor[i] = o;
  }
}
__global__ __launch_bounds__(256) void k_fill(const int* __restrict__ src,
                                              const int* __restrict__ dst,
                                              int* cursor, int* csr, int E) {
  int e = blockIdx.x * blockDim.x + threadIdx.x;
  if (e < E) {
    int p = atomicAdd(&cursor[dst[e]], 1);
    csr[p] = src[e];
  }
}
// ---------------------------------------------------------------------------

// Y[row][j] = (sum_k X[row][k] * W[k][j]) [*dinv[row]] [+bias[j]]
// Block = 64 rows x NOUT cols; thread = 4 rows x NC cols (cols tx+16j).
// OUTBF: write Y as bf16 (RNE) else fp32.
template<int K, int NOUT, bool SCALE, bool BIAS, bool OUTBF>
__global__ __launch_bounds__(256) void k_gemm(
    const float* __restrict__ X, const float* __restrict__ W,
    const float* __restrict__ dinv, const float* __restrict__ bias,
    void* __restrict__ Yv, int nrows)
{
  constexpr int LDX = 68;
  constexpr int LDW = K + 4;
  constexpr int NC  = (NOUT + 15) / 16;
  __shared__ float Xs[64 * LDX];
  __shared__ float WT[NC * 16 * LDW];

  const int t  = threadIdx.x;
  const int tx = t & 15;
  const int ty = t >> 4;
  const int r0 = blockIdx.x * 64;

  for (int idx = t; idx < K * NOUT; idx += 256) {
    int k = idx / NOUT, col = idx - k * NOUT;
    WT[col * LDW + k] = W[idx];
  }

  float acc[4][NC];
  #pragma unroll
  for (int i = 0; i < 4; ++i)
    #pragma unroll
    for (int j = 0; j < NC; ++j) acc[i][j] = 0.f;

  for (int kt = 0; kt < K; kt += 64) {
    __syncthreads();
    #pragma unroll
    for (int it = 0; it < 4; ++it) {
      int f4  = it * 256 + t;
      int row = f4 >> 4;
      int kk  = (f4 & 15) * 4;
      int gr  = r0 + row; if (gr >= nrows) gr = nrows - 1;
      *(float4*)&Xs[row * LDX + kk] = *(const float4*)&X[(size_t)gr * K + kt + kk];
    }
    __syncthreads();

    #pragma unroll 4
    for (int k = 0; k < 64; k += 4) {
      float4 xv[4], wv[NC];
      #pragma unroll
      for (int i = 0; i < 4; ++i)
        xv[i] = *(const float4*)&Xs[(ty * 4 + i) * LDX + k];
      #pragma unroll
      for (int j = 0; j < NC; ++j)
        wv[j] = *(const float4*)&WT[(tx + 16 * j) * LDW + kt + k];
      #pragma unroll
      for (int i = 0; i < 4; ++i)
        #pragma unroll
        for (int j = 0; j < NC; ++j) {
          acc[i][j] = fmaf(xv[i].x, wv[j].x, acc[i][j]);
          acc[i][j] = fmaf(xv[i].y, wv[j].y, acc[i][j]);
          acc[i][j] = fmaf(xv[i].z, wv[j].z, acc[i][j]);
          acc[i][j] = fmaf(xv[i].w, wv[j].w, acc[i][j]);
        }
    }
  }

  #pragma unroll
  for (int i = 0; i < 4; ++i) {
    const int row = r0 + ty * 4 + i;
    if (row >= nrows) continue;
    const float sc = SCALE ? dinv[row] : 1.f;
    #pragma unroll
    for (int j = 0; j < NC; ++j) {
      const int col = tx + 16 * j;
      if (col < NOUT) {
        float v = acc[i][j];
        if constexpr (SCALE) v *= sc;
        if constexpr (BIAS)  v += bias[col];
        if constexpr (OUTBF)
          ((unsigned short*)Yv)[(size_t)row * NOUT + col] = f2bf(v);
        else
          ((float*)Yv)[(size_t)row * NOUT + col] = v;
      }
    }
  }
}

// Pull-aggregate + fused epilogue. One wave per node, lane = feature.
// hs is bf16 (gather row = 128B); accumulate fp32; out fp32.
__global__ __launch_bounds__(256) void k_pull(
    const unsigned short* __restrict__ hs, const int* __restrict__ csr,
    const int* __restrict__ offs, const int* __restrict__ endo,
    const float* __restrict__ dinv, const float* __restrict__ bias,
    float* __restrict__ out, int n)
{
  const int node = blockIdx.x * 4 + (threadIdx.x >> 6);
  if (node >= n) return;
  const int lane = threadIdx.x & 63;

  const int beg = offs[node];
  const int m   = endo[node] - beg;

  float acc0 = bf2f(hs[(size_t)node * 64 + lane]);   // self term
  float acc1 = 0.f;

  for (int base = 0; base < m; base += 64) {
    const int kk = (m - base < 64) ? (m - base) : 64;
    const int myidx = (base + lane < m) ? csr[beg + base + lane] : 0;
    int i = 0;
    for (; i + 4 <= kk; i += 4) {
      int s0 = __shfl(myidx, i + 0);
      int s1 = __shfl(myidx, i + 1);
      int s2 = __shfl(myidx, i + 2);
      int s3 = __shfl(myidx, i + 3);
      float v0 = bf2f(hs[(size_t)s0 * 64 + lane]);
      float v1 = bf2f(hs[(size_t)s1 * 64 + lane]);
      float v2 = bf2f(hs[(size_t)s2 * 64 + lane]);
      float v3 = bf2f(hs[(size_t)s3 * 64 + lane]);
      acc0 += v0; acc1 += v1; acc0 += v2; acc1 += v3;
    }
    for (; i < kk; ++i) {
      int s = __shfl(myidx, i);
      acc0 += bf2f(hs[(size_t)s * 64 + lane]);
    }
  }
  float v = fmaf(dinv[node], acc0 + acc1, bias[lane]);
  out[(size_t)node * 64 + lane] = fmaxf(v, 0.f);
}

extern "C" void kernel_launch(void* const* d_in, const int* in_sizes, int n_in,
                              void* d_out, int out_size, void* d_ws, size_t ws_size,
                              hipStream_t stream) {
  const float* x  = (const float*)d_in[0];
  const int*   ei = (const int*)d_in[1];
  const float* W1 = (const float*)d_in[2];
  const float* b1 = (const float*)d_in[3];
  const float* W2 = (const float*)d_in[4];
  const float* b2 = (const float*)d_in[5];
  const float* Wh = (const float*)d_in[6];
  const float* bh = (const float*)d_in[7];
  float* out = (float*)d_out;

  const int N = in_sizes[0] / 128;
  const int E = in_sizes[1] / 2;
  const int* src = ei;
  const int* dst = ei + E;

  auto align_up = [](size_t v, size_t a) { return (v + a - 1) & ~(a - 1); };
  char* ws = (char*)d_ws;
  size_t off = 0;
  int*   cnt    = (int*)(ws + off);   off = align_up(off + (size_t)N * 4, 256);
  float* dinv   = (float*)(ws + off); off = align_up(off + (size_t)N * 4, 256);
  int*   offs   = (int*)(ws + off);   off = align_up(off + (size_t)N * 4, 256);
  int*   endo   = (int*)(ws + off);   off = align_up(off + (size_t)N * 4, 256);
  int*   bsum   = (int*)(ws + off);   off = align_up(off + 256 * 4, 256);
  int*   bhist  = (int*)(ws + off);   off = align_up(off + NB_MAX * 4, 256);
  int*   boff   = (int*)(ws + off);   off = align_up(off + (NB_MAX + 1) * 4, 256);
  int*   gcur   = (int*)(ws + off);   off = align_up(off + NB_MAX * 4, 256);
  int*   csr    = (int*)(ws + off);   off = align_up(off + (size_t)E * 4, 256);
  int*   binned = (int*)(ws + off);   off = align_up(off + (size_t)E * 4, 256);
  unsigned short* A = (unsigned short*)(ws + off); off = align_up(off + (size_t)N * 64 * 2, 256);
  float* B      = (float*)(ws + off); off = align_up(off + (size_t)N * 64 * 4, 256);
  (void)ws_size;

  const int TB = 256;
  const int gN = (N + TB - 1) / TB;
  const int gE = (E + TB - 1) / TB;
  const int NBk = (N + BN - 1) >> BIN_SHIFT;      // buckets
  const int gGemm = (N + 63) / 64;
  const int gPull = (N + 3) / 4;
  const int gBin  = (E + BIN_CHUNK - 1) / BIN_CHUNK;

  if (NBk <= NB_MAX) {
    // ---- local CSR build (no scattered global atomics) ----
    k_zero <<<1, TB, 0, stream>>>(bhist, NBk);
    k_bhist<<<512, TB, 0, stream>>>(dst, bhist, E, NBk);
    k_bscan<<<1, TB, 0, stream>>>(bhist, boff, gcur, NBk, E);
    k_bin  <<<gBin, TB, 0, stream>>>(src, dst, gcur, binned, E);
    k_csr  <<<NBk, TB, 0, stream>>>(binned, boff, offs, endo, dinv, csr, N);
  } else {
    // ---- fallback: global count/scan/fill ----
    k_zero <<<gN, TB, 0, stream>>>(cnt, N);
    k_count<<<gE, TB, 0, stream>>>(dst, cnt, E);
    k_dinv <<<gN, TB, 0, stream>>>(cnt, dinv, N);
    const int nb1 = (N + 1023) / 1024;
    k_scan1<<<nb1, TB, 0, stream>>>(cnt, offs, bsum, N);
    k_scan2<<<1,  TB, 0, stream>>>(bsum, nb1);
    k_scan3<<<gN, TB, 0, stream>>>(offs, bsum, endo, N);
    k_fill <<<gE, TB, 0, stream>>>(src, dst, endo, csr, E);
  }

  // ---- layer 1 ----  A = hs1 (bf16) = (x@W1)*dinv ; B = h1 (fp32)
  k_gemm<128, 64, true, false, true><<<gGemm, TB, 0, stream>>>(x, W1, dinv, nullptr, A, N);
  k_pull<<<gPull, TB, 0, stream>>>(A, csr, offs, endo, dinv, b1, B, N);

  // ---- layer 2 ----  A = hs2 (bf16) = (h1@W2)*dinv ; B = h2 (fp32)
  k_gemm<64, 64, true, false, true><<<gGemm, TB, 0, stream>>>(B, W2, dinv, nullptr, A, N);
  k_pull<<<gPull, TB, 0, stream>>>(A, csr, offs, endo, dinv, b2, B, N);

  // ---- head ----  out = h2 @ Wh + bh  (fp32)
  k_gemm<64, 40, false, true, false><<<gGemm, TB, 0, stream>>>(B, Wh, nullptr, bh, out, N);
}

// Round 10
// 232.459 us; speedup vs baseline: 2.1246x; 1.0374x over previous
//
#include <hip/hip_runtime.h>
#include <hip/hip_bf16.h>

// ---------------------------------------------------------------------------
// GCN: h1 = relu(gcnconv(x, W1, b1)); h2 = relu(gcnconv(h1, W2, b2));
//      out = h2 @ Wh + bh
// gcnconv(x,W,b)[d] = dinv[d] * ( sum_{e: src->d} hs[src] + hs[d] ) + b
//   where hs = (x@W) * dinv[row],  dinv = rsqrt(indeg + 1)
// CSR build: bucket hist -> bucket scan -> bin-sort -> per-bucket LDS CSR.
// hs stored bf16. k_pull: 2 edges per wave (32 lanes each, 4B/lane) ->
// 256B per gather instruction, 4 in flight; cross-half shfl_xor reduce.
// ---------------------------------------------------------------------------

#define BIN_SHIFT 9
#define BN        (1 << BIN_SHIFT)     // 512 nodes per bucket
#define NB_MAX    256
#define BIN_CHUNK 4096                 // edges per k_bin block

__device__ __forceinline__ float bf2f(unsigned short u) {
  union { unsigned i; float f; } c; c.i = ((unsigned)u) << 16; return c.f;
}
__device__ __forceinline__ unsigned short f2bf(float f) {
  union { float f; unsigned i; } c; c.f = f;
  unsigned r = c.i + 0x7FFFu + ((c.i >> 16) & 1u);   // RNE
  return (unsigned short)(r >> 16);
}

__global__ __launch_bounds__(256) void k_zero(int* p, int n) {
  int i = blockIdx.x * blockDim.x + threadIdx.x;
  if (i < n) p[i] = 0;
}

// ---- bucket-level histogram (LDS pre-aggregated)
__global__ __launch_bounds__(256) void k_bhist(const int* __restrict__ dst,
                                               int* bhist, int E, int nb) {
  __shared__ int lh[NB_MAX];
  lh[threadIdx.x] = 0;
  __syncthreads();
  for (int i = blockIdx.x * 256 + threadIdx.x; i < E; i += gridDim.x * 256)
    atomicAdd(&lh[dst[i] >> BIN_SHIFT], 1);
  __syncthreads();
  int v = lh[threadIdx.x];
  if (threadIdx.x < nb && v) atomicAdd(&bhist[threadIdx.x], v);
}

// ---- scan bucket counts -> boff[nb+1], gcur
__global__ __launch_bounds__(256) void k_bscan(const int* __restrict__ bhist,
                                               int* boff, int* gcur, int nb, int E) {
  __shared__ int sh[256];
  const int t = threadIdx.x;
  int v = (t < nb) ? bhist[t] : 0;
  sh[t] = v;
  __syncthreads();
  for (int d = 1; d < 256; d <<= 1) {
    int x = (t >= d) ? sh[t - d] : 0;
    __syncthreads();
    sh[t] += x;
    __syncthreads();
  }
  if (t < nb) { int e = sh[t] - v; boff[t] = e; gcur[t] = e; }
  if (t == 0) boff[nb] = E;
}

// ---- split-sort edges into buckets by dst>>BIN_SHIFT (coalesced drain)
__global__ __launch_bounds__(256) void k_bin(
    const int* __restrict__ src, const int* __restrict__ dst,
    int* gcur, int* __restrict__ binned, int E)
{
  __shared__ int  hist[NB_MAX];
  __shared__ int  excl[NB_MAX];
  __shared__ int  lcur[NB_MAX];
  __shared__ int  gbase[NB_MAX];
  __shared__ int2 stage[BIN_CHUNK];

  const int t = threadIdx.x;
  const int base = blockIdx.x * BIN_CHUNK;
  const int m = min(BIN_CHUNK, E - base);

  int2 pr[BIN_CHUNK / 256];
  int nmine = 0;
  #pragma unroll
  for (int i = 0; i < BIN_CHUNK / 256; ++i) {
    int idx = t + 256 * i;
    if (idx < m) {
      pr[i].x = src[base + idx];
      pr[i].y = dst[base + idx];
      nmine = i + 1;
    }
  }

  hist[t] = 0;
  __syncthreads();
  #pragma unroll
  for (int i = 0; i < BIN_CHUNK / 256; ++i)
    if (i < nmine) atomicAdd(&hist[pr[i].y >> BIN_SHIFT], 1);
  __syncthreads();

  const int mycnt = hist[t];
  for (int d = 1; d < 256; d <<= 1) {
    int v = (t >= d) ? hist[t - d] : 0;
    __syncthreads();
    hist[t] += v;
    __syncthreads();
  }
  {
    int e = hist[t] - mycnt;
    excl[t] = e;
    lcur[t] = e;
    gbase[t] = mycnt ? atomicAdd(&gcur[t], mycnt) : 0;
  }
  __syncthreads();

  #pragma unroll
  for (int i = 0; i < BIN_CHUNK / 256; ++i)
    if (i < nmine) {
      int b = pr[i].y >> BIN_SHIFT;
      int p = atomicAdd(&lcur[b], 1);
      stage[p] = pr[i];
    }
  __syncthreads();

  for (int i = t; i < m; i += 256) {
    int2 pp = stage[i];
    int b = pp.y >> BIN_SHIFT;
    binned[gbase[b] + (i - excl[b])] =
        (pp.x << BIN_SHIFT) | (pp.y & (BN - 1));
  }
}

// ---- per-bucket CSR build: degree hist + scan + offs/endo/dinv + scatter
__global__ __launch_bounds__(256) void k_csr(
    const int* __restrict__ binned, const int* __restrict__ boff,
    int* __restrict__ offs, int* __restrict__ endo,
    float* __restrict__ dinv, int* __restrict__ csr, int n)
{
  __shared__ int cnt_l[BN];
  __shared__ int tsum[256];
  __shared__ int lcur[BN];
  const int t = threadIdx.x;
  const int b = blockIdx.x;
  const int base = boff[b];
  const int end  = boff[b + 1];
  const int n0 = b << BIN_SHIFT;

  cnt_l[t] = 0; cnt_l[t + 256] = 0;
  __syncthreads();
  for (int i = base + t; i < end; i += 256)
    atomicAdd(&cnt_l[binned[i] & (BN - 1)], 1);
  __syncthreads();

  const int c0 = cnt_l[2 * t];
  const int c1 = cnt_l[2 * t + 1];
  const int s = c0 + c1;
  tsum[t] = s;
  __syncthreads();
  for (int d = 1; d < 256; d <<= 1) {
    int v = (t >= d) ? tsum[t - d] : 0;
    __syncthreads();
    tsum[t] += v;
    __syncthreads();
  }
  const int ex = tsum[t] - s;
  const int e0 = ex, e1 = ex + c0;
  const int g0 = n0 + 2 * t, g1 = g0 + 1;
  if (g0 < n) {
    offs[g0] = base + e0; endo[g0] = base + e1;
    dinv[g0] = rsqrtf((float)(c0 + 1));
  }
  if (g1 < n) {
    offs[g1] = base + e1; endo[g1] = base + e1 + c1;
    dinv[g1] = rsqrtf((float)(c1 + 1));
  }
  lcur[2 * t] = e0;
  lcur[2 * t + 1] = e1;
  __syncthreads();
  for (int i = base + t; i < end; i += 256) {
    int v = binned[i];
    int p = atomicAdd(&lcur[v & (BN - 1)], 1);
    csr[base + p] = v >> BIN_SHIFT;
  }
}

// ---------------- fallback path (N too big for bucket build) ---------------
__global__ __launch_bounds__(256) void k_count(const int* __restrict__ dst, int* cnt, int E) {
  int e = blockIdx.x * blockDim.x + threadIdx.x;
  if (e < E) atomicAdd(&cnt[dst[e]], 1);
}
__global__ __launch_bounds__(256) void k_dinv(const int* __restrict__ cnt, float* dinv, int n) {
  int i = blockIdx.x * blockDim.x + threadIdx.x;
  if (i < n) dinv[i] = rsqrtf((float)(cnt[i] + 1));
}
__global__ __launch_bounds__(256) void k_scan1(const int* __restrict__ cnt,
                                               int* offs, int* bsum, int n) {
  __shared__ int sh[256];
  const int t = threadIdx.x;
  const int base = blockIdx.x * 1024 + t * 4;
  int v0 = 0, v1 = 0, v2 = 0, v3 = 0;
  if (base + 0 < n) v0 = cnt[base + 0];
  if (base + 1 < n) v1 = cnt[base + 1];
  if (base + 2 < n) v2 = cnt[base + 2];
  if (base + 3 < n) v3 = cnt[base + 3];
  const int s = v0 + v1 + v2 + v3;
  sh[t] = s;
  __syncthreads();
  for (int d = 1; d < 256; d <<= 1) {
    int x = (t >= d) ? sh[t - d] : 0;
    __syncthreads();
    sh[t] += x;
    __syncthreads();
  }
  int o = sh[t] - s;
  if (t == 255) bsum[blockIdx.x] = sh[255];
  if (base + 0 < n) { offs[base + 0] = o; o += v0; }
  if (base + 1 < n) { offs[base + 1] = o; o += v1; }
  if (base + 2 < n) { offs[base + 2] = o; o += v2; }
  if (base + 3 < n) { offs[base + 3] = o; o += v3; }
}
__global__ __launch_bounds__(256) void k_scan2(int* bsum, int nb) {
  __shared__ int sh[256];
  const int t = threadIdx.x;
  int v = (t < nb) ? bsum[t] : 0;
  sh[t] = v;
  __syncthreads();
  for (int d = 1; d < 256; d <<= 1) {
    int x = (t >= d) ? sh[t - d] : 0;
    __syncthreads();
    sh[t] += x;
    __syncthreads();
  }
  if (t < nb) bsum[t] = sh[t] - v;
}
__global__ __launch_bounds__(256) void k_scan3(int* offs, const int* __restrict__ bsum,
                                               int* cursor, int n) {
  int i = blockIdx.x * blockDim.x + threadIdx.x;
  if (i < n) {
    int o = offs[i] + bsum[i >> 10];
    offs[i] = o;
    cursor[i] = o;
  }
}
__global__ __launch_bounds__(256) void k_fill(const int* __restrict__ src,
                                              const int* __restrict__ dst,
                                              int* cursor, int* csr, int E) {
  int e = blockIdx.x * blockDim.x + threadIdx.x;
  if (e < E) {
    int p = atomicAdd(&cursor[dst[e]], 1);
    csr[p] = src[e];
  }
}
// ---------------------------------------------------------------------------

// Y[row][j] = (sum_k X[row][k] * W[k][j]) [*dinv[row]] [+bias[j]]
// Block = 64 rows x NOUT cols; thread = 4 rows x NC cols (cols tx+16j).
// OUTBF: write Y as bf16 (RNE) else fp32.
template<int K, int NOUT, bool SCALE, bool BIAS, bool OUTBF>
__global__ __launch_bounds__(256) void k_gemm(
    const float* __restrict__ X, const float* __restrict__ W,
    const float* __restrict__ dinv, const float* __restrict__ bias,
    void* __restrict__ Yv, int nrows)
{
  constexpr int LDX = 68;
  constexpr int LDW = K + 4;
  constexpr int NC  = (NOUT + 15) / 16;
  __shared__ float Xs[64 * LDX];
  __shared__ float WT[NC * 16 * LDW];

  const int t  = threadIdx.x;
  const int tx = t & 15;
  const int ty = t >> 4;
  const int r0 = blockIdx.x * 64;

  for (int idx = t; idx < K * NOUT; idx += 256) {
    int k = idx / NOUT, col = idx - k * NOUT;
    WT[col * LDW + k] = W[idx];
  }

  float acc[4][NC];
  #pragma unroll
  for (int i = 0; i < 4; ++i)
    #pragma unroll
    for (int j = 0; j < NC; ++j) acc[i][j] = 0.f;

  for (int kt = 0; kt < K; kt += 64) {
    __syncthreads();
    #pragma unroll
    for (int it = 0; it < 4; ++it) {
      int f4  = it * 256 + t;
      int row = f4 >> 4;
      int kk  = (f4 & 15) * 4;
      int gr  = r0 + row; if (gr >= nrows) gr = nrows - 1;
      *(float4*)&Xs[row * LDX + kk] = *(const float4*)&X[(size_t)gr * K + kt + kk];
    }
    __syncthreads();

    #pragma unroll 4
    for (int k = 0; k < 64; k += 4) {
      float4 xv[4], wv[NC];
      #pragma unroll
      for (int i = 0; i < 4; ++i)
        xv[i] = *(const float4*)&Xs[(ty * 4 + i) * LDX + k];
      #pragma unroll
      for (int j = 0; j < NC; ++j)
        wv[j] = *(const float4*)&WT[(tx + 16 * j) * LDW + kt + k];
      #pragma unroll
      for (int i = 0; i < 4; ++i)
        #pragma unroll
        for (int j = 0; j < NC; ++j) {
          acc[i][j] = fmaf(xv[i].x, wv[j].x, acc[i][j]);
          acc[i][j] = fmaf(xv[i].y, wv[j].y, acc[i][j]);
          acc[i][j] = fmaf(xv[i].z, wv[j].z, acc[i][j]);
          acc[i][j] = fmaf(xv[i].w, wv[j].w, acc[i][j]);
        }
    }
  }

  #pragma unroll
  for (int i = 0; i < 4; ++i) {
    const int row = r0 + ty * 4 + i;
    if (row >= nrows) continue;
    const float sc = SCALE ? dinv[row] : 1.f;
    #pragma unroll
    for (int j = 0; j < NC; ++j) {
      const int col = tx + 16 * j;
      if (col < NOUT) {
        float v = acc[i][j];
        if constexpr (SCALE) v *= sc;
        if constexpr (BIAS)  v += bias[col];
        if constexpr (OUTBF)
          ((unsigned short*)Yv)[(size_t)row * NOUT + col] = f2bf(v);
        else
          ((float*)Yv)[(size_t)row * NOUT + col] = v;
      }
    }
  }
}

// Pull-aggregate + fused epilogue. One wave per node; the wave's two 32-lane
// halves process DIFFERENT edges (lane = 2 features via 4B bf16x2 load) ->
// 256B per gather instruction, 4 in flight. Cross-half shfl_xor(32) reduce;
// self term added once after reduction; lanes 0-31 write fp32 float2.
__global__ __launch_bounds__(256) void k_pull(
    const unsigned short* __restrict__ hs, const int* __restrict__ csr,
    const int* __restrict__ offs, const int* __restrict__ endo,
    const float* __restrict__ dinv, const float* __restrict__ bias,
    float* __restrict__ out, int n)
{
  const int node = blockIdx.x * 4 + (threadIdx.x >> 6);
  if (node >= n) return;
  const int lane = threadIdx.x & 63;
  const int h    = lane >> 5;            // half 0/1 -> even/odd edges
  const int fcol = (lane & 31) * 2;      // this lane's feature pair

  const int beg = offs[node];
  const int m   = endo[node] - beg;

  float ax = 0.f, ay = 0.f;

  for (int base = 0; base < m; base += 64) {
    const int kk = (m - base < 64) ? (m - base) : 64;
    const int myidx = (base + lane < m) ? csr[beg + base + lane] : 0;
    const int npair = kk >> 1;
    int i = 0;
    for (; i + 4 <= npair; i += 4) {
      int sa0 = __shfl(myidx, 2*(i+0)), sb0 = __shfl(myidx, 2*(i+0)+1);
      int sa1 = __shfl(myidx, 2*(i+1)), sb1 = __shfl(myidx, 2*(i+1)+1);
      int sa2 = __shfl(myidx, 2*(i+2)), sb2 = __shfl(myidx, 2*(i+2)+1);
      int sa3 = __shfl(myidx, 2*(i+3)), sb3 = __shfl(myidx, 2*(i+3)+1);
      int s0 = h ? sb0 : sa0;
      int s1 = h ? sb1 : sa1;
      int s2 = h ? sb2 : sa2;
      int s3 = h ? sb3 : sa3;
      unsigned u0 = *(const unsigned*)&hs[(size_t)s0 * 64 + fcol];
      unsigned u1 = *(const unsigned*)&hs[(size_t)s1 * 64 + fcol];
      unsigned u2 = *(const unsigned*)&hs[(size_t)s2 * 64 + fcol];
      unsigned u3 = *(const unsigned*)&hs[(size_t)s3 * 64 + fcol];
      ax += bf2f((unsigned short)u0); ay += bf2f((unsigned short)(u0 >> 16));
      ax += bf2f((unsigned short)u1); ay += bf2f((unsigned short)(u1 >> 16));
      ax += bf2f((unsigned short)u2); ay += bf2f((unsigned short)(u2 >> 16));
      ax += bf2f((unsigned short)u3); ay += bf2f((unsigned short)(u3 >> 16));
    }
    for (; i < npair; ++i) {
      int sa = __shfl(myidx, 2*i), sb = __shfl(myidx, 2*i + 1);
      int s = h ? sb : sa;
      unsigned u = *(const unsigned*)&hs[(size_t)s * 64 + fcol];
      ax += bf2f((unsigned short)u); ay += bf2f((unsigned short)(u >> 16));
    }
    if (kk & 1) {
      int s = __shfl(myidx, kk - 1);
      if (h == 0) {
        unsigned u = *(const unsigned*)&hs[(size_t)s * 64 + fcol];
        ax += bf2f((unsigned short)u); ay += bf2f((unsigned short)(u >> 16));
      }
    }
  }

  // combine halves: feature f = h0 + h1
  ax += __shfl_xor(ax, 32);
  ay += __shfl_xor(ay, 32);

  if (h == 0) {
    unsigned u = *(const unsigned*)&hs[(size_t)node * 64 + fcol];  // self term
    float sx = ax + bf2f((unsigned short)u);
    float sy = ay + bf2f((unsigned short)(u >> 16));
    const float dv = dinv[node];
    const float2 bb = *(const float2*)&bias[fcol];
    float2 o;
    o.x = fmaxf(fmaf(dv, sx, bb.x), 0.f);
    o.y = fmaxf(fmaf(dv, sy, bb.y), 0.f);
    *(float2*)&out[(size_t)node * 64 + fcol] = o;
  }
}

extern "C" void kernel_launch(void* const* d_in, const int* in_sizes, int n_in,
                              void* d_out, int out_size, void* d_ws, size_t ws_size,
                              hipStream_t stream) {
  const float* x  = (const float*)d_in[0];
  const int*   ei = (const int*)d_in[1];
  const float* W1 = (const float*)d_in[2];
  const float* b1 = (const float*)d_in[3];
  const float* W2 = (const float*)d_in[4];
  const float* b2 = (const float*)d_in[5];
  const float* Wh = (const float*)d_in[6];
  const float* bh = (const float*)d_in[7];
  float* out = (float*)d_out;

  const int N = in_sizes[0] / 128;
  const int E = in_sizes[1] / 2;
  const int* src = ei;
  const int* dst = ei + E;

  auto align_up = [](size_t v, size_t a) { return (v + a - 1) & ~(a - 1); };
  char* ws = (char*)d_ws;
  size_t off = 0;
  int*   cnt    = (int*)(ws + off);   off = align_up(off + (size_t)N * 4, 256);
  float* dinv   = (float*)(ws + off); off = align_up(off + (size_t)N * 4, 256);
  int*   offs   = (int*)(ws + off);   off = align_up(off + (size_t)N * 4, 256);
  int*   endo   = (int*)(ws + off);   off = align_up(off + (size_t)N * 4, 256);
  int*   bsum   = (int*)(ws + off);   off = align_up(off + 256 * 4, 256);
  int*   bhist  = (int*)(ws + off);   off = align_up(off + NB_MAX * 4, 256);
  int*   boff   = (int*)(ws + off);   off = align_up(off + (NB_MAX + 1) * 4, 256);
  int*   gcur   = (int*)(ws + off);   off = align_up(off + NB_MAX * 4, 256);
  int*   csr    = (int*)(ws + off);   off = align_up(off + (size_t)E * 4, 256);
  int*   binned = (int*)(ws + off);   off = align_up(off + (size_t)E * 4, 256);
  unsigned short* A = (unsigned short*)(ws + off); off = align_up(off + (size_t)N * 64 * 2, 256);
  float* B      = (float*)(ws + off); off = align_up(off + (size_t)N * 64 * 4, 256);
  (void)ws_size;

  const int TB = 256;
  const int gN = (N + TB - 1) / TB;
  const int gE = (E + TB - 1) / TB;
  const int NBk = (N + BN - 1) >> BIN_SHIFT;      // buckets
  const int gGemm = (N + 63) / 64;
  const int gPull = (N + 3) / 4;
  const int gBin  = (E + BIN_CHUNK - 1) / BIN_CHUNK;

  if (NBk <= NB_MAX) {
    // ---- local CSR build (no scattered global atomics) ----
    k_zero <<<1, TB, 0, stream>>>(bhist, NBk);
    k_bhist<<<512, TB, 0, stream>>>(dst, bhist, E, NBk);
    k_bscan<<<1, TB, 0, stream>>>(bhist, boff, gcur, NBk, E);
    k_bin  <<<gBin, TB, 0, stream>>>(src, dst, gcur, binned, E);
    k_csr  <<<NBk, TB, 0, stream>>>(binned, boff, offs, endo, dinv, csr, N);
  } else {
    // ---- fallback: global count/scan/fill ----
    k_zero <<<gN, TB, 0, stream>>>(cnt, N);
    k_count<<<gE, TB, 0, stream>>>(dst, cnt, E);
    k_dinv <<<gN, TB, 0, stream>>>(cnt, dinv, N);
    const int nb1 = (N + 1023) / 1024;
    k_scan1<<<nb1, TB, 0, stream>>>(cnt, offs, bsum, N);
    k_scan2<<<1,  TB, 0, stream>>>(bsum, nb1);
    k_scan3<<<gN, TB, 0, stream>>>(offs, bsum, endo, N);
    k_fill <<<gE, TB, 0, stream>>>(src, dst, endo, csr, E);
  }

  // ---- layer 1 ----  A = hs1 (bf16) = (x@W1)*dinv ; B = h1 (fp32)
  k_gemm<128, 64, true, false, true><<<gGemm, TB, 0, stream>>>(x, W1, dinv, nullptr, A, N);
  k_pull<<<gPull, TB, 0, stream>>>(A, csr, offs, endo, dinv, b1, B, N);

  // ---- layer 2 ----  A = hs2 (bf16) = (h1@W2)*dinv ; B = h2 (fp32)
  k_gemm<64, 64, true, false, true><<<gGemm, TB, 0, stream>>>(B, W2, dinv, nullptr, A, N);
  k_pull<<<gPull, TB, 0, stream>>>(A, csr, offs, endo, dinv, b2, B, N);

  // ---- head ----  out = h2 @ Wh + bh  (fp32)
  k_gemm<64, 40, false, true, false><<<gGemm, TB, 0, stream>>>(B, Wh, nullptr, bh, out, N);
}